// Round 9
// baseline (892.963 us; speedup 1.0000x reference)
//
#include <hip/hip_runtime.h>
#include <hip/hip_bf16.h>

typedef __attribute__((ext_vector_type(8))) short short8;
typedef __attribute__((ext_vector_type(4))) short svec4;
typedef __attribute__((ext_vector_type(8))) __bf16 bf16x8;
typedef __attribute__((ext_vector_type(4))) float f32x4;

#define NN 100000
#define HD 384
#define K1T 22   // GEMM1 k-tiles (704/32; 700 padded)
#define K2T 24   // GEMM2 k-tiles ([h1 | he])
#define NBLK 98
#define PANB 12288   // one A-panel: [32 rows][384 B] (192 bf16 cols)

// d_ws byte offsets
#define OFF_B1  0
#define OFF_B2  540672
#define OFF_T   1130496
#define OFF_V   1139712
#define OFF_BI  1141248
#define OFF_IDX 1142784
#define OFF_CNT 1942784
#define OFF_OFFS 1943568
#define OFF_TOT 1944352

union Frag { short s[8]; bf16x8 v; };

__device__ __forceinline__ short f2bf(float f) {
  union { __bf16 h; short s; } u;
  u.h = (__bf16)f;
  return u.s;
}

__device__ __forceinline__ float elu(float v) {
  return v > 0.f ? v : __expf(v) - 1.f;
}

__global__ void prep_kernel(const float* __restrict__ W1g, const float* __restrict__ b1g,
                            const float* __restrict__ W2g, const float* __restrict__ b2g,
                            const float* __restrict__ W1e, const float* __restrict__ b1e,
                            const float* __restrict__ W2e, const float* __restrict__ b2e,
                            char* __restrict__ ws) {
  int t = blockIdx.x * 256 + threadIdx.x;
  short* B1 = (short*)(ws + OFF_B1);
  short* B2 = (short*)(ws + OFF_B2);
  float* Tt = (float*)(ws + OFF_T);
  float* Vt = (float*)(ws + OFF_V);
  float* Bi = (float*)(ws + OFF_BI);
  if (t < 33792) {                       // B1: (nt,kt,lane) -> 8 shorts
    int lane = t & 63, rest = t >> 6;
    int kt = rest % K1T, nt = rest / K1T;
    int col = nt * 16 + (lane & 15);
    int kb = kt * 32 + (lane >> 4) * 8;
    short8 v;
#pragma unroll
    for (int i = 0; i < 8; ++i) {
      int k = kb + i;
      v[i] = (k < 700) ? f2bf(W1g[k * 384 + col]) : (short)0;
    }
    *(short8*)(B1 + (size_t)t * 8) = v;
  } else if (t < 70656) {                // B2
    int t2 = t - 33792;
    int lane = t2 & 63, rest = t2 >> 6;
    int kt = rest % K2T, nt = rest / K2T;
    int col = nt * 16 + (lane & 15);
    int kb = kt * 32 + (lane >> 4) * 8;
    short8 v;
#pragma unroll
    for (int i = 0; i < 8; ++i) {
      int k = kb + i;
      v[i] = (k < 384) ? f2bf(W2g[k * 384 + col]) : f2bf(W2e[(k - 384) * 384 + col]);
    }
    *(short8*)(B2 + (size_t)t2 * 8) = v;
  } else if (t < 73728) {                // tables
    int r = t - 70656;
    int which = r / 384, c = r % 384;
    if (which < 6)       Tt[r] = W1e[which * 384 + c] + b1e[c];
    else if (which == 6) Vt[c] = W1e[6 * 384 + c];
    else                 Bi[c] = b2g[c] + b2e[c];
  }
}

__global__ void count_kernel(const float* __restrict__ isf1, const float* __restrict__ isf2,
                             char* __restrict__ ws) {
  int g = blockIdx.y;
  const float* isf = g ? isf2 : isf1;
  int i = blockIdx.x * 1024 + threadIdx.x;
  bool face = (i < NN) && (isf[i] > 0.5f);
  unsigned long long b = __ballot(face);
  __shared__ int wc[16];
  int lane = threadIdx.x & 63, wid = threadIdx.x >> 6;
  if (lane == 0) wc[wid] = __popcll(b);
  __syncthreads();
  if (threadIdx.x == 0) {
    int s = 0;
#pragma unroll
    for (int w = 0; w < 16; ++w) s += wc[w];
    ((int*)(ws + OFF_CNT))[g * NBLK + blockIdx.x] = s;
  }
}

__global__ void scan_kernel(char* __restrict__ ws) {
  int t = threadIdx.x;
  if (t < 2) {
    const int* cnt = (const int*)(ws + OFF_CNT) + t * NBLK;
    int* offs = (int*)(ws + OFF_OFFS) + t * NBLK;
    int* tot = (int*)(ws + OFF_TOT);
    int run = 0;
    for (int b = 0; b < NBLK; ++b) { offs[b] = run; run += cnt[b]; }
    tot[t] = run;
  }
}

__global__ void compact_kernel(const float* __restrict__ isf1, const float* __restrict__ isf2,
                               char* __restrict__ ws) {
  int g = blockIdx.y;
  const float* isf = g ? isf2 : isf1;
  const int* offs = (const int*)(ws + OFF_OFFS) + g * NBLK;
  int totF = ((const int*)(ws + OFF_TOT))[g];
  int* idx = (int*)(ws + OFF_IDX) + g * NN;
  int bx = blockIdx.x;
  int i = bx * 1024 + threadIdx.x;
  bool valid = i < NN;
  bool face = valid && (isf[i] > 0.5f);
  unsigned long long bf = __ballot(face);
  unsigned long long bv = __ballot(valid);
  int lane = threadIdx.x & 63, wid = threadIdx.x >> 6;
  __shared__ int wF[16], wV[16];
  if (lane == 0) { wF[wid] = __popcll(bf); wV[wid] = __popcll(bv); }
  __syncthreads();
  int baseF = 0, baseV = 0;
  for (int w = 0; w < wid; ++w) { baseF += wF[w]; baseV += wV[w]; }
  unsigned long long lmask = (1ull << lane) - 1ull;
  int pF = __popcll(bf & lmask);
  int pV = __popcll(bv & lmask);
  if (face) {
    idx[offs[bx] + baseF + pF] = i;
  } else if (valid) {
    int nfBefore = bx * 1024 - offs[bx];
    int nfIn = (baseV + pV) - (baseF + pF);
    idx[totF + nfBefore + nfIn] = i;
  }
}

// GEMM1 panel compute: NKT k-tiles from panel PAN (row stride 384B, XOR swz).
#define GEMM1_PANEL(PAN, KTBASE, NKT)                                              \
  { const char* pan_ = (PAN);                                                      \
    _Pragma("unroll")                                                              \
    for (int ktL = 0; ktL < (NKT); ++ktL) {                                        \
      Frag a_[2];                                                                  \
      _Pragma("unroll")                                                            \
      for (int m = 0; m < 2; ++m) {                                                \
        int row = m * 16 + lr;                                                     \
        int byte = (row * 384 + ktL * 64 + gq * 16) ^ ((row & 7) << 4);            \
        a_[m].v = *(const bf16x8*)(pan_ + byte);                                   \
      }                                                                            \
      _Pragma("unroll")                                                            \
      for (int n = 0; n < 6; ++n) {                                                \
        bf16x8 b_ = B1[((wid * 6 + n) * K1T + (KTBASE) + ktL) * 64 + lane];        \
        _Pragma("unroll")                                                          \
        for (int m = 0; m < 2; ++m)                                                \
          acc[m][n] = __builtin_amdgcn_mfma_f32_16x16x32_bf16(a_[m].v, b_, acc[m][n], 0, 0, 0); \
      }                                                                            \
    } }

// 32 gathered face rows/block, 256 thr = 4 waves, N-split-4: wave = 32r x 96c,
// acc[2][6] reused for both GEMMs. A staged as 4 k-panels (192,192,192,128 cols)
// ping-ponged in 2x12KB LDS with issue-early/write-late (T14): global loads for
// panel p+1 issue BEFORE panel p's MFMAs, ds_write after. h1 [32][768B]=24KB
// overlays the panels. LDS 24.7KB -> 6 blocks/CU (2x R5 occupancy).
__global__ __launch_bounds__(256, 6) void face_embed_kernel(
    const float* __restrict__ x1, const int* __restrict__ et1, const float* __restrict__ ar1,
    const float* __restrict__ x2, const int* __restrict__ et2, const float* __restrict__ ar2,
    const float* __restrict__ b1g, const char* __restrict__ ws,
    float* __restrict__ out) {
  const int g = blockIdx.y;
  const float* x = g ? x2 : x1;
  const int* et  = g ? et2 : et1;
  const float* ar = g ? ar2 : ar1;
  float* o = out + (size_t)g * NN * HD;
  const int* idx = (const int*)(ws + OFF_IDX) + g * NN;
  const int totF = ((const int*)(ws + OFF_TOT))[g];
  const int nFB = (totF + 31) >> 5;
  const int bx = blockIdx.x;
  const int tid = threadIdx.x;

  if (bx >= nFB) {                       // ---- zero path (32 non-face rows/block) ----
    int totN = NN - totF;
    int base = (bx - nFB) * 32;
    if (base >= totN) return;
    const int* idxN = idx + totF;
    f32x4 z = {0.f, 0.f, 0.f, 0.f};
#pragma unroll
    for (int it = 0; it < 12; ++it) {
      int c = tid + it * 256;            // 32 rows x 96 f32x4 chunks = 3072
      int r = c / 96, cc = c % 96;
      if (base + r < totN) {
        int node = idxN[base + r];
        *(f32x4*)(o + (size_t)node * HD + cc * 4) = z;
      }
    }
    return;
  }

  // ---- GEMM path ----
  __shared__ char buf[24576];            // panels [0,12288)+[12288,24576); h1 [0,24576)
  __shared__ int sN[32];

  const bf16x8* B1 = (const bf16x8*)(ws + OFF_B1);
  const bf16x8* B2 = (const bf16x8*)(ws + OFF_B2);
  const float* Tg  = (const float*)(ws + OFF_T);
  const float* Vg  = (const float*)(ws + OFF_V);
  const float* Big = (const float*)(ws + OFF_BI);

  const int row0 = bx * 32;
  if (tid < 32) sN[tid] = (row0 + tid < totF) ? idx[row0 + tid] : -1;
  __syncthreads();

  const int wid = tid >> 6, lane = tid & 63;
  const int lr = lane & 15, gq = lane >> 4;

  float b1c[6], b2c[6];
#pragma unroll
  for (int n = 0; n < 6; ++n) {
    int col = (wid * 6 + n) * 16 + lr;
    b1c[n] = b1g[col];
    b2c[n] = Big[col];
  }
  // entity params for the 2 A-row-frags of this lane
  int nde[2]; float nda[2];
#pragma unroll
  for (int m = 0; m < 2; ++m) {
    int node = sN[m * 16 + lr];
    if (node >= 0) { nde[m] = et[node]; nda[m] = ar[node]; }
    else           { nde[m] = 0;        nda[m] = 0.f; }
  }

  // ---- staging helpers: issue (global->reg) / write (reg->LDS) ----
  f32x4 st[6];
  auto issue6 = [&](int p) {             // 192 cols: 32r x 48 chunks = 1536
#pragma unroll
    for (int it = 0; it < 6; ++it) {
      int c = tid + it * 256;
      int r = c / 48, cc = c % 48;
      int node = sN[r];
      st[it] = (node >= 0) ? *(const f32x4*)(x + (size_t)node * 700 + p * 192 + cc * 4)
                           : (f32x4){0.f, 0.f, 0.f, 0.f};
    }
  };
  auto write6 = [&](char* pan) {
#pragma unroll
    for (int it = 0; it < 6; ++it) {
      int c = tid + it * 256;
      int r = c / 48, cc = c % 48;
      svec4 pk;
#pragma unroll
      for (int i = 0; i < 4; ++i) pk[i] = f2bf(st[it][i]);
      int byte = (r * 384 + cc * 8) ^ ((r & 7) << 4);
      *(svec4*)(pan + byte) = pk;
    }
  };
  auto issue4 = [&]() {                  // panel 3: 128 cols (576..703), pad >=700
#pragma unroll
    for (int it = 0; it < 4; ++it) {
      int c = tid + it * 256;
      int r = c >> 5, cc = c & 31;
      int node = sN[r];
      st[it] = (node >= 0 && cc < 31) ? *(const f32x4*)(x + (size_t)node * 700 + 576 + cc * 4)
                                      : (f32x4){0.f, 0.f, 0.f, 0.f};
    }
  };
  auto write4 = [&](char* pan) {
#pragma unroll
    for (int it = 0; it < 4; ++it) {
      int c = tid + it * 256;
      int r = c >> 5, cc = c & 31;
      svec4 pk;
#pragma unroll
      for (int i = 0; i < 4; ++i) pk[i] = f2bf(st[it][i]);
      int byte = (r * 384 + cc * 8) ^ ((r & 7) << 4);
      *(svec4*)(pan + byte) = pk;
    }
  };

  f32x4 acc[2][6] = {};

  // ======== GEMM1: 4 panels, ping-pong, issue-early/write-late ========
  issue6(0); write6(buf);
  __syncthreads();

  issue6(1);                      // loads fly under panel-0 MFMAs
  GEMM1_PANEL(buf, 0, 6);
  write6(buf + PANB);
  __syncthreads();

  issue6(2);
  GEMM1_PANEL(buf + PANB, 6, 6);
  write6(buf);
  __syncthreads();

  issue4();
  GEMM1_PANEL(buf, 12, 6);
  write4(buf + PANB);
  __syncthreads();

  GEMM1_PANEL(buf + PANB, 18, 4);
  __syncthreads();                // all panel reads done; buf free for h1

  // ======== h1 = elu(acc + b1) -> LDS [32][768B] swizzled; acc reset ========
#pragma unroll
  for (int m = 0; m < 2; ++m)
#pragma unroll
    for (int n = 0; n < 6; ++n) {
      int col = (wid * 6 + n) * 16 + lr;
#pragma unroll
      for (int r2 = 0; r2 < 4; ++r2) {
        int row = m * 16 + 4 * gq + r2;
        float hv = elu(acc[m][n][r2] + b1c[n]);
        int byte = (row * 768 + col * 2) ^ ((row & 15) << 4);
        *(short*)(buf + byte) = f2bf(hv);
      }
    }
  __syncthreads();

#pragma unroll
  for (int m = 0; m < 2; ++m)
#pragma unroll
    for (int n = 0; n < 6; ++n)
      acc[m][n] = (f32x4){0.f, 0.f, 0.f, 0.f};

  // ======== GEMM2: out = [h1|he] @ [W2g;W2e], single loop, he inline ========
  for (int kt = 0; kt < K2T; ++kt) {
    Frag a[2];
    if (kt < 12) {
#pragma unroll
      for (int m = 0; m < 2; ++m) {
        int row = m * 16 + lr;
        int byte = (row * 768 + (kt * 32 + gq * 8) * 2) ^ ((row & 15) << 4);
        a[m].v = *(const bf16x8*)(buf + byte);
      }
    } else {
      int c0 = (kt - 12) * 32 + gq * 8;
#pragma unroll
      for (int m = 0; m < 2; ++m) {
        const float* Tp = Tg + nde[m] * 384 + c0;
        const float* Vp = Vg + c0;
#pragma unroll
        for (int i = 0; i < 8; ++i)
          a[m].s[i] = f2bf(elu(Tp[i] + nda[m] * Vp[i]));
      }
    }
#pragma unroll
    for (int n = 0; n < 6; ++n) {
      bf16x8 b = B2[((wid * 6 + n) * K2T + kt) * 64 + lane];
#pragma unroll
      for (int m = 0; m < 2; ++m)
        acc[m][n] = __builtin_amdgcn_mfma_f32_16x16x32_bf16(a[m].v, b, acc[m][n], 0, 0, 0);
    }
  }

  // ======== epilogue: +bias2, scatter store (384B line-aligned per wave) ========
#pragma unroll
  for (int m = 0; m < 2; ++m) {
#pragma unroll
    for (int r2 = 0; r2 < 4; ++r2) {
      int node = sN[m * 16 + 4 * gq + r2];
      if (node >= 0) {
#pragma unroll
        for (int n = 0; n < 6; ++n) {
          int col = (wid * 6 + n) * 16 + lr;
          o[(size_t)node * HD + col] = acc[m][n][r2] + b2c[n];
        }
      }
    }
  }
}

extern "C" void kernel_launch(void* const* d_in, const int* in_sizes, int n_in,
                              void* d_out, int out_size, void* d_ws, size_t ws_size,
                              hipStream_t stream) {
  (void)n_in; (void)out_size; (void)ws_size; (void)in_sizes;
  const float* x1  = (const float*)d_in[0];
  const float* is1 = (const float*)d_in[1];
  const int*   et1 = (const int*)d_in[2];
  const float* ar1 = (const float*)d_in[3];
  const float* x2  = (const float*)d_in[4];
  const float* is2 = (const float*)d_in[5];
  const int*   et2 = (const int*)d_in[6];
  const float* ar2 = (const float*)d_in[7];
  const float* W1g = (const float*)d_in[8];
  const float* b1g = (const float*)d_in[9];
  const float* W2g = (const float*)d_in[10];
  const float* b2g = (const float*)d_in[11];
  const float* W1e = (const float*)d_in[12];
  const float* b1e = (const float*)d_in[13];
  const float* W2e = (const float*)d_in[14];
  const float* b2e = (const float*)d_in[15];
  float* out = (float*)d_out;
  char* ws = (char*)d_ws;

  prep_kernel<<<dim3(288), dim3(256), 0, stream>>>(W1g, b1g, W2g, b2g, W1e, b1e, W2e, b2e, ws);
  count_kernel<<<dim3(NBLK, 2), dim3(1024), 0, stream>>>(is1, is2, ws);
  scan_kernel<<<dim3(1), dim3(64), 0, stream>>>(ws);
  compact_kernel<<<dim3(NBLK, 2), dim3(1024), 0, stream>>>(is1, is2, ws);

  dim3 grid(NN / 32 + 1, 2);
  face_embed_kernel<<<grid, dim3(256), 0, stream>>>(
      x1, et1, ar1, x2, et2, ar2, b1g, ws, out);
}

// Round 10
// 484.629 us; speedup vs baseline: 1.8426x; 1.8426x over previous
//
#include <hip/hip_runtime.h>
#include <hip/hip_bf16.h>

typedef __attribute__((ext_vector_type(8))) short short8;
typedef __attribute__((ext_vector_type(4))) short svec4;
typedef __attribute__((ext_vector_type(8))) __bf16 bf16x8;
typedef __attribute__((ext_vector_type(4))) float f32x4;

#define NN 100000
#define HD 384
#define K1T 22   // GEMM1 k-tiles (704/32; 700 padded)
#define K2T 24   // GEMM2 k-tiles ([h1 | he])
#define NBLK 98
#define PANB 12288   // one A-panel: [32 rows][384 B] (192 bf16 cols)

// d_ws byte offsets
#define OFF_B1  0
#define OFF_B2  540672
#define OFF_T   1130496
#define OFF_V   1139712
#define OFF_BI  1141248
#define OFF_IDX 1142784
#define OFF_CNT 1942784
#define OFF_OFFS 1943568
#define OFF_TOT 1944352

union Frag { short s[8]; bf16x8 v; };

__device__ __forceinline__ short f2bf(float f) {
  union { __bf16 h; short s; } u;
  u.h = (__bf16)f;
  return u.s;
}

__device__ __forceinline__ float elu(float v) {
  return v > 0.f ? v : __expf(v) - 1.f;
}

__global__ void prep_kernel(const float* __restrict__ W1g, const float* __restrict__ b1g,
                            const float* __restrict__ W2g, const float* __restrict__ b2g,
                            const float* __restrict__ W1e, const float* __restrict__ b1e,
                            const float* __restrict__ W2e, const float* __restrict__ b2e,
                            char* __restrict__ ws) {
  int t = blockIdx.x * 256 + threadIdx.x;
  short* B1 = (short*)(ws + OFF_B1);
  short* B2 = (short*)(ws + OFF_B2);
  float* Tt = (float*)(ws + OFF_T);
  float* Vt = (float*)(ws + OFF_V);
  float* Bi = (float*)(ws + OFF_BI);
  if (t < 33792) {                       // B1: (nt,kt,lane) -> 8 shorts
    int lane = t & 63, rest = t >> 6;
    int kt = rest % K1T, nt = rest / K1T;
    int col = nt * 16 + (lane & 15);
    int kb = kt * 32 + (lane >> 4) * 8;
    short8 v;
#pragma unroll
    for (int i = 0; i < 8; ++i) {
      int k = kb + i;
      v[i] = (k < 700) ? f2bf(W1g[k * 384 + col]) : (short)0;
    }
    *(short8*)(B1 + (size_t)t * 8) = v;
  } else if (t < 70656) {                // B2
    int t2 = t - 33792;
    int lane = t2 & 63, rest = t2 >> 6;
    int kt = rest % K2T, nt = rest / K2T;
    int col = nt * 16 + (lane & 15);
    int kb = kt * 32 + (lane >> 4) * 8;
    short8 v;
#pragma unroll
    for (int i = 0; i < 8; ++i) {
      int k = kb + i;
      v[i] = (k < 384) ? f2bf(W2g[k * 384 + col]) : f2bf(W2e[(k - 384) * 384 + col]);
    }
    *(short8*)(B2 + (size_t)t2 * 8) = v;
  } else if (t < 73728) {                // tables
    int r = t - 70656;
    int which = r / 384, c = r % 384;
    if (which < 6)       Tt[r] = W1e[which * 384 + c] + b1e[c];
    else if (which == 6) Vt[c] = W1e[6 * 384 + c];
    else                 Bi[c] = b2g[c] + b2e[c];
  }
}

__global__ void count_kernel(const float* __restrict__ isf1, const float* __restrict__ isf2,
                             char* __restrict__ ws) {
  int g = blockIdx.y;
  const float* isf = g ? isf2 : isf1;
  int i = blockIdx.x * 1024 + threadIdx.x;
  bool face = (i < NN) && (isf[i] > 0.5f);
  unsigned long long b = __ballot(face);
  __shared__ int wc[16];
  int lane = threadIdx.x & 63, wid = threadIdx.x >> 6;
  if (lane == 0) wc[wid] = __popcll(b);
  __syncthreads();
  if (threadIdx.x == 0) {
    int s = 0;
#pragma unroll
    for (int w = 0; w < 16; ++w) s += wc[w];
    ((int*)(ws + OFF_CNT))[g * NBLK + blockIdx.x] = s;
  }
}

__global__ void scan_kernel(char* __restrict__ ws) {
  int t = threadIdx.x;
  if (t < 2) {
    const int* cnt = (const int*)(ws + OFF_CNT) + t * NBLK;
    int* offs = (int*)(ws + OFF_OFFS) + t * NBLK;
    int* tot = (int*)(ws + OFF_TOT);
    int run = 0;
    for (int b = 0; b < NBLK; ++b) { offs[b] = run; run += cnt[b]; }
    tot[t] = run;
  }
}

__global__ void compact_kernel(const float* __restrict__ isf1, const float* __restrict__ isf2,
                               char* __restrict__ ws) {
  int g = blockIdx.y;
  const float* isf = g ? isf2 : isf1;
  const int* offs = (const int*)(ws + OFF_OFFS) + g * NBLK;
  int totF = ((const int*)(ws + OFF_TOT))[g];
  int* idx = (int*)(ws + OFF_IDX) + g * NN;
  int bx = blockIdx.x;
  int i = bx * 1024 + threadIdx.x;
  bool valid = i < NN;
  bool face = valid && (isf[i] > 0.5f);
  unsigned long long bf = __ballot(face);
  unsigned long long bv = __ballot(valid);
  int lane = threadIdx.x & 63, wid = threadIdx.x >> 6;
  __shared__ int wF[16], wV[16];
  if (lane == 0) { wF[wid] = __popcll(bf); wV[wid] = __popcll(bv); }
  __syncthreads();
  int baseF = 0, baseV = 0;
  for (int w = 0; w < wid; ++w) { baseF += wF[w]; baseV += wV[w]; }
  unsigned long long lmask = (1ull << lane) - 1ull;
  int pF = __popcll(bf & lmask);
  int pV = __popcll(bv & lmask);
  if (face) {
    idx[offs[bx] + baseF + pF] = i;
  } else if (valid) {
    int nfBefore = bx * 1024 - offs[bx];
    int nfIn = (baseV + pV) - (baseF + pF);
    idx[totF + nfBefore + nfIn] = i;
  }
}

// GEMM1 panel compute: NKT k-tiles from panel PAN (row stride 384B, XOR swz).
#define GEMM1_PANEL(PAN, KTBASE, NKT)                                              \
  { const char* pan_ = (PAN);                                                      \
    _Pragma("unroll")                                                              \
    for (int ktL = 0; ktL < (NKT); ++ktL) {                                        \
      Frag a_[2];                                                                  \
      _Pragma("unroll")                                                            \
      for (int m = 0; m < 2; ++m) {                                                \
        int row = m * 16 + lr;                                                     \
        int byte = (row * 384 + ktL * 64 + gq * 16) ^ ((row & 7) << 4);            \
        a_[m].v = *(const bf16x8*)(pan_ + byte);                                   \
      }                                                                            \
      _Pragma("unroll")                                                            \
      for (int n = 0; n < 6; ++n) {                                                \
        bf16x8 b_ = B1[((wid * 6 + n) * K1T + (KTBASE) + ktL) * 64 + lane];        \
        _Pragma("unroll")                                                          \
        for (int m = 0; m < 2; ++m)                                                \
          acc[m][n] = __builtin_amdgcn_mfma_f32_16x16x32_bf16(a_[m].v, b_, acc[m][n], 0, 0, 0); \
      }                                                                            \
    } }

// 32 gathered face rows/block, 256 thr = 4 waves, N-split-4: wave = 32r x 96c,
// acc[2][6] reused for both GEMMs. A staged as 4 k-panels ping-ponged in 2x12KB
// LDS with issue-early/write-late (T14). h1 [32][768B]=24KB overlays panels.
// launch_bounds(256,4): VGPR cap 128 (per-SIMD pool=512; 6 waves capped at 85
// and spilled acc -> 1.17GB scratch traffic in R9). 4 blocks/CU, no spill.
__global__ __launch_bounds__(256, 4) void face_embed_kernel(
    const float* __restrict__ x1, const int* __restrict__ et1, const float* __restrict__ ar1,
    const float* __restrict__ x2, const int* __restrict__ et2, const float* __restrict__ ar2,
    const float* __restrict__ b1g, const char* __restrict__ ws,
    float* __restrict__ out) {
  const int g = blockIdx.y;
  const float* x = g ? x2 : x1;
  const int* et  = g ? et2 : et1;
  const float* ar = g ? ar2 : ar1;
  float* o = out + (size_t)g * NN * HD;
  const int* idx = (const int*)(ws + OFF_IDX) + g * NN;
  const int totF = ((const int*)(ws + OFF_TOT))[g];
  const int nFB = (totF + 31) >> 5;
  const int bx = blockIdx.x;
  const int tid = threadIdx.x;

  if (bx >= nFB) {                       // ---- zero path (32 non-face rows/block) ----
    int totN = NN - totF;
    int base = (bx - nFB) * 32;
    if (base >= totN) return;
    const int* idxN = idx + totF;
    f32x4 z = {0.f, 0.f, 0.f, 0.f};
#pragma unroll
    for (int it = 0; it < 12; ++it) {
      int c = tid + it * 256;            // 32 rows x 96 f32x4 chunks = 3072
      int r = c / 96, cc = c % 96;
      if (base + r < totN) {
        int node = idxN[base + r];
        *(f32x4*)(o + (size_t)node * HD + cc * 4) = z;
      }
    }
    return;
  }

  // ---- GEMM path ----
  __shared__ char buf[24576];            // panels [0,12288)+[12288,24576); h1 [0,24576)
  __shared__ int sN[32];

  const bf16x8* B1 = (const bf16x8*)(ws + OFF_B1);
  const bf16x8* B2 = (const bf16x8*)(ws + OFF_B2);
  const float* Tg  = (const float*)(ws + OFF_T);
  const float* Vg  = (const float*)(ws + OFF_V);
  const float* Big = (const float*)(ws + OFF_BI);

  const int row0 = bx * 32;
  if (tid < 32) sN[tid] = (row0 + tid < totF) ? idx[row0 + tid] : -1;
  __syncthreads();

  const int wid = tid >> 6, lane = tid & 63;
  const int lr = lane & 15, gq = lane >> 4;

  float b1c[6], b2c[6];
#pragma unroll
  for (int n = 0; n < 6; ++n) {
    int col = (wid * 6 + n) * 16 + lr;
    b1c[n] = b1g[col];
    b2c[n] = Big[col];
  }
  // entity params for the 2 A-row-frags of this lane
  int nde[2]; float nda[2];
#pragma unroll
  for (int m = 0; m < 2; ++m) {
    int node = sN[m * 16 + lr];
    if (node >= 0) { nde[m] = et[node]; nda[m] = ar[node]; }
    else           { nde[m] = 0;        nda[m] = 0.f; }
  }

  // ---- staging helpers: issue (global->reg) / write (reg->LDS) ----
  f32x4 st[6];
  auto issue6 = [&](int p) {             // 192 cols: 32r x 48 chunks = 1536
#pragma unroll
    for (int it = 0; it < 6; ++it) {
      int c = tid + it * 256;
      int r = c / 48, cc = c % 48;
      int node = sN[r];
      st[it] = (node >= 0) ? *(const f32x4*)(x + (size_t)node * 700 + p * 192 + cc * 4)
                           : (f32x4){0.f, 0.f, 0.f, 0.f};
    }
  };
  auto write6 = [&](char* pan) {
#pragma unroll
    for (int it = 0; it < 6; ++it) {
      int c = tid + it * 256;
      int r = c / 48, cc = c % 48;
      svec4 pk;
#pragma unroll
      for (int i = 0; i < 4; ++i) pk[i] = f2bf(st[it][i]);
      int byte = (r * 384 + cc * 8) ^ ((r & 7) << 4);
      *(svec4*)(pan + byte) = pk;
    }
  };
  auto issue4 = [&]() {                  // panel 3: 128 cols (576..703), pad >=700
#pragma unroll
    for (int it = 0; it < 4; ++it) {
      int c = tid + it * 256;
      int r = c >> 5, cc = c & 31;
      int node = sN[r];
      st[it] = (node >= 0 && cc < 31) ? *(const f32x4*)(x + (size_t)node * 700 + 576 + cc * 4)
                                      : (f32x4){0.f, 0.f, 0.f, 0.f};
    }
  };
  auto write4 = [&](char* pan) {
#pragma unroll
    for (int it = 0; it < 4; ++it) {
      int c = tid + it * 256;
      int r = c >> 5, cc = c & 31;
      svec4 pk;
#pragma unroll
      for (int i = 0; i < 4; ++i) pk[i] = f2bf(st[it][i]);
      int byte = (r * 384 + cc * 8) ^ ((r & 7) << 4);
      *(svec4*)(pan + byte) = pk;
    }
  };

  f32x4 acc[2][6] = {};

  // ======== GEMM1: 4 panels, ping-pong, issue-early/write-late ========
  issue6(0); write6(buf);
  __syncthreads();

  issue6(1);                      // loads fly under panel-0 MFMAs
  GEMM1_PANEL(buf, 0, 6);
  write6(buf + PANB);
  __syncthreads();

  issue6(2);
  GEMM1_PANEL(buf + PANB, 6, 6);
  write6(buf);
  __syncthreads();

  issue4();
  GEMM1_PANEL(buf, 12, 6);
  write4(buf + PANB);
  __syncthreads();

  GEMM1_PANEL(buf + PANB, 18, 4);
  __syncthreads();                // all panel reads done; buf free for h1

  // ======== h1 = elu(acc + b1) -> LDS [32][768B] swizzled; acc reset ========
#pragma unroll
  for (int m = 0; m < 2; ++m)
#pragma unroll
    for (int n = 0; n < 6; ++n) {
      int col = (wid * 6 + n) * 16 + lr;
#pragma unroll
      for (int r2 = 0; r2 < 4; ++r2) {
        int row = m * 16 + 4 * gq + r2;
        float hv = elu(acc[m][n][r2] + b1c[n]);
        int byte = (row * 768 + col * 2) ^ ((row & 15) << 4);
        *(short*)(buf + byte) = f2bf(hv);
      }
    }
  __syncthreads();

#pragma unroll
  for (int m = 0; m < 2; ++m)
#pragma unroll
    for (int n = 0; n < 6; ++n)
      acc[m][n] = (f32x4){0.f, 0.f, 0.f, 0.f};

  // ======== GEMM2: out = [h1|he] @ [W2g;W2e], single loop, he inline ========
  for (int kt = 0; kt < K2T; ++kt) {
    Frag a[2];
    if (kt < 12) {
#pragma unroll
      for (int m = 0; m < 2; ++m) {
        int row = m * 16 + lr;
        int byte = (row * 768 + (kt * 32 + gq * 8) * 2) ^ ((row & 15) << 4);
        a[m].v = *(const bf16x8*)(buf + byte);
      }
    } else {
      int c0 = (kt - 12) * 32 + gq * 8;
#pragma unroll
      for (int m = 0; m < 2; ++m) {
        const float* Tp = Tg + nde[m] * 384 + c0;
        const float* Vp = Vg + c0;
#pragma unroll
        for (int i = 0; i < 8; ++i)
          a[m].s[i] = f2bf(elu(Tp[i] + nda[m] * Vp[i]));
      }
    }
#pragma unroll
    for (int n = 0; n < 6; ++n) {
      bf16x8 b = B2[((wid * 6 + n) * K2T + kt) * 64 + lane];
#pragma unroll
      for (int m = 0; m < 2; ++m)
        acc[m][n] = __builtin_amdgcn_mfma_f32_16x16x32_bf16(a[m].v, b, acc[m][n], 0, 0, 0);
    }
  }

  // ======== epilogue: +bias2, scatter store (384B line-aligned per wave) ========
#pragma unroll
  for (int m = 0; m < 2; ++m) {
#pragma unroll
    for (int r2 = 0; r2 < 4; ++r2) {
      int node = sN[m * 16 + 4 * gq + r2];
      if (node >= 0) {
#pragma unroll
        for (int n = 0; n < 6; ++n) {
          int col = (wid * 6 + n) * 16 + lr;
          o[(size_t)node * HD + col] = acc[m][n][r2] + b2c[n];
        }
      }
    }
  }
}

extern "C" void kernel_launch(void* const* d_in, const int* in_sizes, int n_in,
                              void* d_out, int out_size, void* d_ws, size_t ws_size,
                              hipStream_t stream) {
  (void)n_in; (void)out_size; (void)ws_size; (void)in_sizes;
  const float* x1  = (const float*)d_in[0];
  const float* is1 = (const float*)d_in[1];
  const int*   et1 = (const int*)d_in[2];
  const float* ar1 = (const float*)d_in[3];
  const float* x2  = (const float*)d_in[4];
  const float* is2 = (const float*)d_in[5];
  const int*   et2 = (const int*)d_in[6];
  const float* ar2 = (const float*)d_in[7];
  const float* W1g = (const float*)d_in[8];
  const float* b1g = (const float*)d_in[9];
  const float* W2g = (const float*)d_in[10];
  const float* b2g = (const float*)d_in[11];
  const float* W1e = (const float*)d_in[12];
  const float* b1e = (const float*)d_in[13];
  const float* W2e = (const float*)d_in[14];
  const float* b2e = (const float*)d_in[15];
  float* out = (float*)d_out;
  char* ws = (char*)d_ws;

  prep_kernel<<<dim3(288), dim3(256), 0, stream>>>(W1g, b1g, W2g, b2g, W1e, b1e, W2e, b2e, ws);
  count_kernel<<<dim3(NBLK, 2), dim3(1024), 0, stream>>>(is1, is2, ws);
  scan_kernel<<<dim3(1), dim3(64), 0, stream>>>(ws);
  compact_kernel<<<dim3(NBLK, 2), dim3(1024), 0, stream>>>(is1, is2, ws);

  dim3 grid(NN / 32 + 1, 2);
  face_embed_kernel<<<grid, dim3(256), 0, stream>>>(
      x1, et1, ar1, x2, et2, ar2, b1g, ws, out);
}

// Round 11
// 462.176 us; speedup vs baseline: 1.9321x; 1.0486x over previous
//
#include <hip/hip_runtime.h>
#include <hip/hip_bf16.h>

typedef __attribute__((ext_vector_type(8))) short short8;
typedef __attribute__((ext_vector_type(4))) short svec4;
typedef __attribute__((ext_vector_type(8))) __bf16 bf16x8;
typedef __attribute__((ext_vector_type(4))) float f32x4;

#define NN 100000
#define HD 384
#define K1T 22   // GEMM1 k-tiles (704/32; 700 padded)
#define K2T 24   // GEMM2 k-tiles ([h1 | he])
#define NBLK 98
#define PANB 12288   // one A-panel: [32 rows][384 B] (192 bf16 cols)

// d_ws byte offsets
#define OFF_B1  0
#define OFF_B2  540672
#define OFF_T   1130496
#define OFF_V   1139712
#define OFF_BI  1141248
#define OFF_IDX 1142784
#define OFF_CNT 1942784
#define OFF_OFFS 1943568
#define OFF_TOT 1944352
#define OFF_H1  2097152           // h1 frags: per graph 6250 fm * 12 kt * 64 lane * 16B
#define H1_PER_G 76800000ull
#define WS_NEED (OFF_H1 + 2ull * H1_PER_G)   // 155,697,152 B

union Frag { short s[8]; bf16x8 v; };

__device__ __forceinline__ short f2bf(float f) {
  union { __bf16 h; short s; } u;
  u.h = (__bf16)f;
  return u.s;
}

__device__ __forceinline__ float elu(float v) {
  return v > 0.f ? v : __expf(v) - 1.f;
}

__global__ void prep_kernel(const float* __restrict__ W1g, const float* __restrict__ b1g,
                            const float* __restrict__ W2g, const float* __restrict__ b2g,
                            const float* __restrict__ W1e, const float* __restrict__ b1e,
                            const float* __restrict__ W2e, const float* __restrict__ b2e,
                            char* __restrict__ ws) {
  int t = blockIdx.x * 256 + threadIdx.x;
  short* B1 = (short*)(ws + OFF_B1);
  short* B2 = (short*)(ws + OFF_B2);
  float* Tt = (float*)(ws + OFF_T);
  float* Vt = (float*)(ws + OFF_V);
  float* Bi = (float*)(ws + OFF_BI);
  if (t < 33792) {                       // B1: (nt,kt,lane) -> 8 shorts
    int lane = t & 63, rest = t >> 6;
    int kt = rest % K1T, nt = rest / K1T;
    int col = nt * 16 + (lane & 15);
    int kb = kt * 32 + (lane >> 4) * 8;
    short8 v;
#pragma unroll
    for (int i = 0; i < 8; ++i) {
      int k = kb + i;
      v[i] = (k < 700) ? f2bf(W1g[k * 384 + col]) : (short)0;
    }
    *(short8*)(B1 + (size_t)t * 8) = v;
  } else if (t < 70656) {                // B2
    int t2 = t - 33792;
    int lane = t2 & 63, rest = t2 >> 6;
    int kt = rest % K2T, nt = rest / K2T;
    int col = nt * 16 + (lane & 15);
    int kb = kt * 32 + (lane >> 4) * 8;
    short8 v;
#pragma unroll
    for (int i = 0; i < 8; ++i) {
      int k = kb + i;
      v[i] = (k < 384) ? f2bf(W2g[k * 384 + col]) : f2bf(W2e[(k - 384) * 384 + col]);
    }
    *(short8*)(B2 + (size_t)t2 * 8) = v;
  } else if (t < 73728) {                // tables
    int r = t - 70656;
    int which = r / 384, c = r % 384;
    if (which < 6)       Tt[r] = W1e[which * 384 + c] + b1e[c];
    else if (which == 6) Vt[c] = W1e[6 * 384 + c];
    else                 Bi[c] = b2g[c] + b2e[c];
  }
}

__global__ void count_kernel(const float* __restrict__ isf1, const float* __restrict__ isf2,
                             char* __restrict__ ws) {
  int g = blockIdx.y;
  const float* isf = g ? isf2 : isf1;
  int i = blockIdx.x * 1024 + threadIdx.x;
  bool face = (i < NN) && (isf[i] > 0.5f);
  unsigned long long b = __ballot(face);
  __shared__ int wc[16];
  int lane = threadIdx.x & 63, wid = threadIdx.x >> 6;
  if (lane == 0) wc[wid] = __popcll(b);
  __syncthreads();
  if (threadIdx.x == 0) {
    int s = 0;
#pragma unroll
    for (int w = 0; w < 16; ++w) s += wc[w];
    ((int*)(ws + OFF_CNT))[g * NBLK + blockIdx.x] = s;
  }
}

__global__ void scan_kernel(char* __restrict__ ws) {
  int t = threadIdx.x;
  if (t < 2) {
    const int* cnt = (const int*)(ws + OFF_CNT) + t * NBLK;
    int* offs = (int*)(ws + OFF_OFFS) + t * NBLK;
    int* tot = (int*)(ws + OFF_TOT);
    int run = 0;
    for (int b = 0; b < NBLK; ++b) { offs[b] = run; run += cnt[b]; }
    tot[t] = run;
  }
}

__global__ void compact_kernel(const float* __restrict__ isf1, const float* __restrict__ isf2,
                               char* __restrict__ ws) {
  int g = blockIdx.y;
  const float* isf = g ? isf2 : isf1;
  const int* offs = (const int*)(ws + OFF_OFFS) + g * NBLK;
  int totF = ((const int*)(ws + OFF_TOT))[g];
  int* idx = (int*)(ws + OFF_IDX) + g * NN;
  int bx = blockIdx.x;
  int i = bx * 1024 + threadIdx.x;
  bool valid = i < NN;
  bool face = valid && (isf[i] > 0.5f);
  unsigned long long bf = __ballot(face);
  unsigned long long bv = __ballot(valid);
  int lane = threadIdx.x & 63, wid = threadIdx.x >> 6;
  __shared__ int wF[16], wV[16];
  if (lane == 0) { wF[wid] = __popcll(bf); wV[wid] = __popcll(bv); }
  __syncthreads();
  int baseF = 0, baseV = 0;
  for (int w = 0; w < wid; ++w) { baseF += wF[w]; baseV += wV[w]; }
  unsigned long long lmask = (1ull << lane) - 1ull;
  int pF = __popcll(bf & lmask);
  int pV = __popcll(bv & lmask);
  if (face) {
    idx[offs[bx] + baseF + pF] = i;
  } else if (valid) {
    int nfBefore = bx * 1024 - offs[bx];
    int nfIn = (baseV + pV) - (baseF + pF);
    idx[totF + nfBefore + nfIn] = i;
  }
}

// GEMM1 panel compute: NKT k-tiles from panel PAN (row stride 384B, XOR swz).
#define GEMM1_PANEL(PAN, KTBASE, NKT)                                              \
  { const char* pan_ = (PAN);                                                      \
    _Pragma("unroll")                                                              \
    for (int ktL = 0; ktL < (NKT); ++ktL) {                                        \
      Frag a_[2];                                                                  \
      _Pragma("unroll")                                                            \
      for (int m = 0; m < 2; ++m) {                                                \
        int row = m * 16 + lr;                                                     \
        int byte = (row * 384 + ktL * 64 + gq * 16) ^ ((row & 7) << 4);            \
        a_[m].v = *(const bf16x8*)(pan_ + byte);                                   \
      }                                                                            \
      _Pragma("unroll")                                                            \
      for (int n = 0; n < 6; ++n) {                                                \
        bf16x8 b_ = B1[((wid * 6 + n) * K1T + (KTBASE) + ktL) * 64 + lane];        \
        _Pragma("unroll")                                                          \
        for (int m = 0; m < 2; ++m)                                                \
          acc[m][n] = __builtin_amdgcn_mfma_f32_16x16x32_bf16(a_[m].v, b_, acc[m][n], 0, 0, 0); \
      }                                                                            \
    } }

// ============== split path kernel 1: GEMM1 -> h1 frags in ws ==============
// 32 face rows/block, 4 waves N-split. A: 4 direct-staged ping-pong panels
// (192,192,192,128 cols) in 2x12KB. h1 -> LDS -> coalesced frag-order dump.
__global__ __launch_bounds__(256, 3) void g1_kernel(
    const float* __restrict__ x1, const float* __restrict__ x2,
    const float* __restrict__ b1g, char* __restrict__ ws) {
  const int g = blockIdx.y;
  const float* x = g ? x2 : x1;
  const int* idx = (const int*)(ws + OFF_IDX) + g * NN;
  const int totF = ((const int*)(ws + OFF_TOT))[g];
  const int nFB = (totF + 31) >> 5;
  const int bx = blockIdx.x;
  if (bx >= nFB) return;
  const int tid = threadIdx.x;

  __shared__ char buf[24576];            // 2 panels / h1 [32][768B] overlay
  __shared__ int sN[32];

  const bf16x8* B1 = (const bf16x8*)(ws + OFF_B1);
  const int row0 = bx * 32;
  if (tid < 32) sN[tid] = (row0 + tid < totF) ? idx[row0 + tid] : -1;
  __syncthreads();

  const int wid = tid >> 6, lane = tid & 63;
  const int lr = lane & 15, gq = lane >> 4;

  float b1c[6];
#pragma unroll
  for (int n = 0; n < 6; ++n) b1c[n] = b1g[(wid * 6 + n) * 16 + lr];

  // direct staging (load -> cvt -> ds_write, no held regs)
  auto stage6 = [&](int p, char* pan) {  // 192 cols: 1536 chunks
#pragma unroll
    for (int it = 0; it < 6; ++it) {
      int c = tid + it * 256;
      int r = c / 48, cc = c % 48;
      int node = sN[r];
      f32x4 v = (node >= 0) ? *(const f32x4*)(x + (size_t)node * 700 + p * 192 + cc * 4)
                            : (f32x4){0.f, 0.f, 0.f, 0.f};
      svec4 pk;
#pragma unroll
      for (int i = 0; i < 4; ++i) pk[i] = f2bf(v[i]);
      int byte = (r * 384 + cc * 8) ^ ((r & 7) << 4);
      *(svec4*)(pan + byte) = pk;
    }
  };
  auto stage4 = [&](char* pan) {         // 128 cols (576..703, pad >=700)
#pragma unroll
    for (int it = 0; it < 4; ++it) {
      int c = tid + it * 256;
      int r = c >> 5, cc = c & 31;
      int node = sN[r];
      f32x4 v = (node >= 0 && cc < 31) ? *(const f32x4*)(x + (size_t)node * 700 + 576 + cc * 4)
                                       : (f32x4){0.f, 0.f, 0.f, 0.f};
      svec4 pk;
#pragma unroll
      for (int i = 0; i < 4; ++i) pk[i] = f2bf(v[i]);
      int byte = (r * 384 + cc * 8) ^ ((r & 7) << 4);
      *(svec4*)(pan + byte) = pk;
    }
  };

  f32x4 acc[2][6] = {};
  char* b0 = buf;
  char* b1 = buf + PANB;

  stage6(0, b0);
  __syncthreads();
  stage6(1, b1);  GEMM1_PANEL(b0, 0, 6);
  __syncthreads();
  stage6(2, b0);  GEMM1_PANEL(b1, 6, 6);
  __syncthreads();
  stage4(b1);     GEMM1_PANEL(b0, 12, 6);
  __syncthreads();
  GEMM1_PANEL(b1, 18, 4);
  __syncthreads();                       // panel reads done; buf free for h1

  // h1 = elu(acc + b1) -> LDS [32][768B] swizzled
#pragma unroll
  for (int m = 0; m < 2; ++m)
#pragma unroll
    for (int n = 0; n < 6; ++n) {
      int col = (wid * 6 + n) * 16 + lr;
#pragma unroll
      for (int r2 = 0; r2 < 4; ++r2) {
        int row = m * 16 + 4 * gq + r2;
        float hv = elu(acc[m][n][r2] + b1c[n]);
        int byte = (row * 768 + col * 2) ^ ((row & 15) << 4);
        *(short*)(buf + byte) = f2bf(hv);
      }
    }
  __syncthreads();

  // dump h1 frags to ws: ((fm)*12 + kt)*64 + lane, 16B each, coalesced
  f32x4* h1w = (f32x4*)(ws + OFF_H1 + (size_t)g * H1_PER_G);
  const int fm0 = 2 * bx;
#pragma unroll
  for (int it = 0; it < 6; ++it) {
    int c = tid + it * 256;              // 1536 chunks
    int l = c & 63, rest = c >> 6;
    int kt = rest % 12, m = rest / 12;
    int row = m * 16 + (l & 15);
    int col0 = kt * 32 + (l >> 4) * 8;
    int byte = (row * 768 + col0 * 2) ^ ((row & 15) << 4);
    h1w[(size_t)((fm0 + m) * 12 + kt) * 64 + l] = *(const f32x4*)(buf + byte);
  }
}

// ============== split path kernel 2: GEMM2 from h1 frags (no LDS tile, no barriers) ==============
__global__ __launch_bounds__(256, 3) void g2_kernel(
    const int* __restrict__ et1, const float* __restrict__ ar1,
    const int* __restrict__ et2, const float* __restrict__ ar2,
    const char* __restrict__ ws, float* __restrict__ out) {
  const int g = blockIdx.y;
  const int* et  = g ? et2 : et1;
  const float* ar = g ? ar2 : ar1;
  float* o = out + (size_t)g * NN * HD;
  const int* idx = (const int*)(ws + OFF_IDX) + g * NN;
  const int totF = ((const int*)(ws + OFF_TOT))[g];
  const int nFB = (totF + 31) >> 5;
  const int bx = blockIdx.x;
  const int tid = threadIdx.x;

  if (bx >= nFB) {                       // ---- zero path ----
    int totN = NN - totF;
    int base = (bx - nFB) * 32;
    if (base >= totN) return;
    const int* idxN = idx + totF;
    f32x4 z = {0.f, 0.f, 0.f, 0.f};
#pragma unroll
    for (int it = 0; it < 12; ++it) {
      int c = tid + it * 256;
      int r = c / 96, cc = c % 96;
      if (base + r < totN) {
        int node = idxN[base + r];
        *(f32x4*)(o + (size_t)node * HD + cc * 4) = z;
      }
    }
    return;
  }

  __shared__ int sN[32];
  const int row0 = bx * 32;
  if (tid < 32) sN[tid] = (row0 + tid < totF) ? idx[row0 + tid] : -1;
  __syncthreads();

  const bf16x8* B2 = (const bf16x8*)(ws + OFF_B2);
  const float* Tg  = (const float*)(ws + OFF_T);
  const float* Vg  = (const float*)(ws + OFF_V);
  const float* Big = (const float*)(ws + OFF_BI);
  const f32x4* h1w = (const f32x4*)(ws + OFF_H1 + (size_t)g * H1_PER_G);

  const int wid = tid >> 6, lane = tid & 63;
  const int lr = lane & 15, gq = lane >> 4;
  const int fm0 = 2 * bx;

  float b2c[6];
#pragma unroll
  for (int n = 0; n < 6; ++n) b2c[n] = Big[(wid * 6 + n) * 16 + lr];
  int nde[2]; float nda[2];
#pragma unroll
  for (int m = 0; m < 2; ++m) {
    int node = sN[m * 16 + lr];
    if (node >= 0) { nde[m] = et[node]; nda[m] = ar[node]; }
    else           { nde[m] = 0;        nda[m] = 0.f; }
  }

  f32x4 acc[2][6] = {};
  for (int kt = 0; kt < K2T; ++kt) {
    Frag a[2];
    if (kt < 12) {
#pragma unroll
      for (int m = 0; m < 2; ++m) {
        f32x4 t = h1w[(size_t)((fm0 + m) * 12 + kt) * 64 + lane];
        a[m].v = __builtin_bit_cast(bf16x8, t);
      }
    } else {
      int c0 = (kt - 12) * 32 + gq * 8;
#pragma unroll
      for (int m = 0; m < 2; ++m) {
        const float* Tp = Tg + nde[m] * 384 + c0;
        const float* Vp = Vg + c0;
#pragma unroll
        for (int i = 0; i < 8; ++i)
          a[m].s[i] = f2bf(elu(Tp[i] + nda[m] * Vp[i]));
      }
    }
#pragma unroll
    for (int n = 0; n < 6; ++n) {
      bf16x8 b = B2[((wid * 6 + n) * K2T + kt) * 64 + lane];
#pragma unroll
      for (int m = 0; m < 2; ++m)
        acc[m][n] = __builtin_amdgcn_mfma_f32_16x16x32_bf16(a[m].v, b, acc[m][n], 0, 0, 0);
    }
  }

#pragma unroll
  for (int m = 0; m < 2; ++m) {
#pragma unroll
    for (int r2 = 0; r2 < 4; ++r2) {
      int node = sN[m * 16 + 4 * gq + r2];
      if (node >= 0) {
#pragma unroll
        for (int n = 0; n < 6; ++n) {
          int col = (wid * 6 + n) * 16 + lr;
          o[(size_t)node * HD + col] = acc[m][n][r2] + b2c[n];
        }
      }
    }
  }
}

// ============== fallback: proven R5 fused kernel (362 us) ==============
__global__ __launch_bounds__(256, 3) void face_embed_fused(
    const float* __restrict__ x1, const int* __restrict__ et1, const float* __restrict__ ar1,
    const float* __restrict__ x2, const int* __restrict__ et2, const float* __restrict__ ar2,
    const float* __restrict__ b1g, const char* __restrict__ ws,
    float* __restrict__ out) {
  const int g = blockIdx.y;
  const float* x = g ? x2 : x1;
  const int* et  = g ? et2 : et1;
  const float* ar = g ? ar2 : ar1;
  float* o = out + (size_t)g * NN * HD;
  const int* idx = (const int*)(ws + OFF_IDX) + g * NN;
  const int totF = ((const int*)(ws + OFF_TOT))[g];
  const int nFB = (totF + 31) >> 5;
  const int bx = blockIdx.x;
  const int tid = threadIdx.x;

  if (bx >= nFB) {
    int totN = NN - totF;
    int base = (bx - nFB) * 32;
    if (base >= totN) return;
    const int* idxN = idx + totF;
    f32x4 z = {0.f, 0.f, 0.f, 0.f};
#pragma unroll
    for (int it = 0; it < 12; ++it) {
      int c = tid + it * 256;
      int r = c / 96, cc = c % 96;
      if (base + r < totN) {
        int node = idxN[base + r];
        *(f32x4*)(o + (size_t)node * HD + cc * 4) = z;
      }
    }
    return;
  }

  __shared__ char buf[49152];
  __shared__ int sN[32];
  char* As = buf;
  char* h1s = buf;

  const bf16x8* B1 = (const bf16x8*)(ws + OFF_B1);
  const bf16x8* B2 = (const bf16x8*)(ws + OFF_B2);
  const float* Tg  = (const float*)(ws + OFF_T);
  const float* Vg  = (const float*)(ws + OFF_V);
  const float* Big = (const float*)(ws + OFF_BI);

  const int row0 = bx * 32;
  if (tid < 32) {
    sN[tid] = (row0 + tid < totF) ? idx[row0 + tid] : -1;
    int byte = (tid * 1408 + 1400) ^ ((tid & 7) << 4);
    *(unsigned long long*)(As + byte) = 0ull;
  }
  __syncthreads();

#pragma unroll 4
  for (int it = 0; it < 22; ++it) {
    int c = tid + it * 256;
    if (c < 5600) {
      int r = c / 175, cc = c % 175;
      int node = sN[r];
      if (node >= 0) {
        f32x4 v = *(const f32x4*)(x + (size_t)node * 700 + cc * 4);
        svec4 p;
#pragma unroll
        for (int i = 0; i < 4; ++i) p[i] = f2bf(v[i]);
        int byte = (r * 1408 + cc * 8) ^ ((r & 7) << 4);
        *(svec4*)(As + byte) = p;
      }
    }
  }

  const int wid = tid >> 6, lane = tid & 63;
  const int lr = lane & 15, gq = lane >> 4;

  float b1c[6], b2c[6];
#pragma unroll
  for (int n = 0; n < 6; ++n) {
    int col = (wid * 6 + n) * 16 + lr;
    b1c[n] = b1g[col];
    b2c[n] = Big[col];
  }
  __syncthreads();

  f32x4 acc[2][6] = {};
  for (int kt = 0; kt < K1T; ++kt) {
    Frag a[2];
#pragma unroll
    for (int m = 0; m < 2; ++m) {
      int row = m * 16 + lr;
      int byte = (row * 1408 + kt * 64 + gq * 16) ^ ((row & 7) << 4);
      a[m].v = *(const bf16x8*)(As + byte);
    }
#pragma unroll
    for (int n = 0; n < 6; ++n) {
      bf16x8 b = B1[((wid * 6 + n) * K1T + kt) * 64 + lane];
#pragma unroll
      for (int m = 0; m < 2; ++m)
        acc[m][n] = __builtin_amdgcn_mfma_f32_16x16x32_bf16(a[m].v, b, acc[m][n], 0, 0, 0);
    }
  }
  __syncthreads();

#pragma unroll
  for (int m = 0; m < 2; ++m)
#pragma unroll
    for (int n = 0; n < 6; ++n) {
      int col = (wid * 6 + n) * 16 + lr;
#pragma unroll
      for (int r2 = 0; r2 < 4; ++r2) {
        int row = m * 16 + 4 * gq + r2;
        float hv = elu(acc[m][n][r2] + b1c[n]);
        int byte = (row * 768 + col * 2) ^ ((row & 15) << 4);
        *(short*)(h1s + byte) = f2bf(hv);
      }
    }
  __syncthreads();

  int nde[2]; float nda[2];
#pragma unroll
  for (int m = 0; m < 2; ++m) {
    int node = sN[m * 16 + lr];
    if (node >= 0) { nde[m] = et[node]; nda[m] = ar[node]; }
    else           { nde[m] = 0;        nda[m] = 0.f; }
  }

  f32x4 acc2[2][6] = {};
  for (int kt = 0; kt < K2T; ++kt) {
    Frag a[2];
    if (kt < 12) {
#pragma unroll
      for (int m = 0; m < 2; ++m) {
        int row = m * 16 + lr;
        int byte = (row * 768 + (kt * 32 + gq * 8) * 2) ^ ((row & 15) << 4);
        a[m].v = *(const bf16x8*)(h1s + byte);
      }
    } else {
      int c0 = (kt - 12) * 32 + gq * 8;
#pragma unroll
      for (int m = 0; m < 2; ++m) {
        const float* Tp = Tg + nde[m] * 384 + c0;
        const float* Vp = Vg + c0;
#pragma unroll
        for (int i = 0; i < 8; ++i)
          a[m].s[i] = f2bf(elu(Tp[i] + nda[m] * Vp[i]));
      }
    }
#pragma unroll
    for (int n = 0; n < 6; ++n) {
      bf16x8 b = B2[((wid * 6 + n) * K2T + kt) * 64 + lane];
#pragma unroll
      for (int m = 0; m < 2; ++m)
        acc2[m][n] = __builtin_amdgcn_mfma_f32_16x16x32_bf16(a[m].v, b, acc2[m][n], 0, 0, 0);
    }
  }

#pragma unroll
  for (int m = 0; m < 2; ++m) {
#pragma unroll
    for (int r2 = 0; r2 < 4; ++r2) {
      int node = sN[m * 16 + 4 * gq + r2];
      if (node >= 0) {
#pragma unroll
        for (int n = 0; n < 6; ++n) {
          int col = (wid * 6 + n) * 16 + lr;
          o[(size_t)node * HD + col] = acc2[m][n][r2] + b2c[n];
        }
      }
    }
  }
}

extern "C" void kernel_launch(void* const* d_in, const int* in_sizes, int n_in,
                              void* d_out, int out_size, void* d_ws, size_t ws_size,
                              hipStream_t stream) {
  (void)n_in; (void)out_size; (void)in_sizes;
  const float* x1  = (const float*)d_in[0];
  const float* is1 = (const float*)d_in[1];
  const int*   et1 = (const int*)d_in[2];
  const float* ar1 = (const float*)d_in[3];
  const float* x2  = (const float*)d_in[4];
  const float* is2 = (const float*)d_in[5];
  const int*   et2 = (const int*)d_in[6];
  const float* ar2 = (const float*)d_in[7];
  const float* W1g = (const float*)d_in[8];
  const float* b1g = (const float*)d_in[9];
  const float* W2g = (const float*)d_in[10];
  const float* b2g = (const float*)d_in[11];
  const float* W1e = (const float*)d_in[12];
  const float* b1e = (const float*)d_in[13];
  const float* W2e = (const float*)d_in[14];
  const float* b2e = (const float*)d_in[15];
  float* out = (float*)d_out;
  char* ws = (char*)d_ws;

  prep_kernel<<<dim3(288), dim3(256), 0, stream>>>(W1g, b1g, W2g, b2g, W1e, b1e, W2e, b2e, ws);
  count_kernel<<<dim3(NBLK, 2), dim3(1024), 0, stream>>>(is1, is2, ws);
  scan_kernel<<<dim3(1), dim3(64), 0, stream>>>(ws);
  compact_kernel<<<dim3(NBLK, 2), dim3(1024), 0, stream>>>(is1, is2, ws);

  dim3 grid(NN / 32 + 1, 2);
  if (ws_size >= WS_NEED) {
    g1_kernel<<<grid, dim3(256), 0, stream>>>(x1, x2, b1g, ws);
    g2_kernel<<<grid, dim3(256), 0, stream>>>(et1, ar1, et2, ar2, ws, out);
  } else {
    face_embed_fused<<<grid, dim3(256), 0, stream>>>(
        x1, et1, ar1, x2, et2, ar2, b1g, ws, out);
  }
}

// Round 12
// 400.306 us; speedup vs baseline: 2.2307x; 1.1546x over previous
//
#include <hip/hip_runtime.h>
#include <hip/hip_bf16.h>

typedef __attribute__((ext_vector_type(8))) short short8;
typedef __attribute__((ext_vector_type(4))) short svec4;
typedef __attribute__((ext_vector_type(8))) __bf16 bf16x8;
typedef __attribute__((ext_vector_type(4))) float f32x4;

#define NN 100000
#define HD 384
#define K1T 22   // GEMM1 k-tiles (704/32; 700 padded)
#define K2T 24   // GEMM2 k-tiles ([h1 | he])
#define NBLK 98

// d_ws byte offsets
#define OFF_B1  0
#define OFF_B2  540672
#define OFF_T   1130496
#define OFF_V   1139712
#define OFF_BI  1141248
#define OFF_IDX 1142784
#define OFF_CNT 1942784
#define OFF_OFFS 1943568
#define OFF_TOT 1944352

union Frag { short s[8]; bf16x8 v; };

__device__ __forceinline__ short f2bf(float f) {
  union { __bf16 h; short s; } u;
  u.h = (__bf16)f;
  return u.s;
}

__device__ __forceinline__ float elu(float v) {
  return v > 0.f ? v : __expf(v) - 1.f;
}

__global__ void prep_kernel(const float* __restrict__ W1g, const float* __restrict__ b1g,
                            const float* __restrict__ W2g, const float* __restrict__ b2g,
                            const float* __restrict__ W1e, const float* __restrict__ b1e,
                            const float* __restrict__ W2e, const float* __restrict__ b2e,
                            char* __restrict__ ws) {
  int t = blockIdx.x * 256 + threadIdx.x;
  short* B1 = (short*)(ws + OFF_B1);
  short* B2 = (short*)(ws + OFF_B2);
  float* Tt = (float*)(ws + OFF_T);
  float* Vt = (float*)(ws + OFF_V);
  float* Bi = (float*)(ws + OFF_BI);
  if (t < 33792) {                       // B1: (nt,kt,lane) -> 8 shorts
    int lane = t & 63, rest = t >> 6;
    int kt = rest % K1T, nt = rest / K1T;
    int col = nt * 16 + (lane & 15);
    int kb = kt * 32 + (lane >> 4) * 8;
    short8 v;
#pragma unroll
    for (int i = 0; i < 8; ++i) {
      int k = kb + i;
      v[i] = (k < 700) ? f2bf(W1g[k * 384 + col]) : (short)0;
    }
    *(short8*)(B1 + (size_t)t * 8) = v;
  } else if (t < 70656) {                // B2
    int t2 = t - 33792;
    int lane = t2 & 63, rest = t2 >> 6;
    int kt = rest % K2T, nt = rest / K2T;
    int col = nt * 16 + (lane & 15);
    int kb = kt * 32 + (lane >> 4) * 8;
    short8 v;
#pragma unroll
    for (int i = 0; i < 8; ++i) {
      int k = kb + i;
      v[i] = (k < 384) ? f2bf(W2g[k * 384 + col]) : f2bf(W2e[(k - 384) * 384 + col]);
    }
    *(short8*)(B2 + (size_t)t2 * 8) = v;
  } else if (t < 73728) {                // tables
    int r = t - 70656;
    int which = r / 384, c = r % 384;
    if (which < 6)       Tt[r] = W1e[which * 384 + c] + b1e[c];
    else if (which == 6) Vt[c] = W1e[6 * 384 + c];
    else                 Bi[c] = b2g[c] + b2e[c];
  }
}

__global__ void count_kernel(const float* __restrict__ isf1, const float* __restrict__ isf2,
                             char* __restrict__ ws) {
  int g = blockIdx.y;
  const float* isf = g ? isf2 : isf1;
  int i = blockIdx.x * 1024 + threadIdx.x;
  bool face = (i < NN) && (isf[i] > 0.5f);
  unsigned long long b = __ballot(face);
  __shared__ int wc[16];
  int lane = threadIdx.x & 63, wid = threadIdx.x >> 6;
  if (lane == 0) wc[wid] = __popcll(b);
  __syncthreads();
  if (threadIdx.x == 0) {
    int s = 0;
#pragma unroll
    for (int w = 0; w < 16; ++w) s += wc[w];
    ((int*)(ws + OFF_CNT))[g * NBLK + blockIdx.x] = s;
  }
}

__global__ void scan_kernel(char* __restrict__ ws) {
  int t = threadIdx.x;
  if (t < 2) {
    const int* cnt = (const int*)(ws + OFF_CNT) + t * NBLK;
    int* offs = (int*)(ws + OFF_OFFS) + t * NBLK;
    int* tot = (int*)(ws + OFF_TOT);
    int run = 0;
    for (int b = 0; b < NBLK; ++b) { offs[b] = run; run += cnt[b]; }
    tot[t] = run;
  }
}

__global__ void compact_kernel(const float* __restrict__ isf1, const float* __restrict__ isf2,
                               char* __restrict__ ws) {
  int g = blockIdx.y;
  const float* isf = g ? isf2 : isf1;
  const int* offs = (const int*)(ws + OFF_OFFS) + g * NBLK;
  int totF = ((const int*)(ws + OFF_TOT))[g];
  int* idx = (int*)(ws + OFF_IDX) + g * NN;
  int bx = blockIdx.x;
  int i = bx * 1024 + threadIdx.x;
  bool valid = i < NN;
  bool face = valid && (isf[i] > 0.5f);
  unsigned long long bf = __ballot(face);
  unsigned long long bv = __ballot(valid);
  int lane = threadIdx.x & 63, wid = threadIdx.x >> 6;
  __shared__ int wF[16], wV[16];
  if (lane == 0) { wF[wid] = __popcll(bf); wV[wid] = __popcll(bv); }
  __syncthreads();
  int baseF = 0, baseV = 0;
  for (int w = 0; w < wid; ++w) { baseF += wF[w]; baseV += wV[w]; }
  unsigned long long lmask = (1ull << lane) - 1ull;
  int pF = __popcll(bf & lmask);
  int pV = __popcll(bv & lmask);
  if (face) {
    idx[offs[bx] + baseF + pF] = i;
  } else if (valid) {
    int nfBefore = bx * 1024 - offs[bx];
    int nfIn = (baseV + pV) - (baseF + pF);
    idx[totF + nfBefore + nfIn] = i;
  }
}

// 32 gathered face rows/block, 4 waves N-split (wave = 32r x 96c), acc[2][6]
// reused for both GEMMs. BARRIER-LIGHT (2 barriers total): GEMM1 reads A-frags
// DIRECTLY from global x (16 rows x one 128B line per kt; all 4 waves share the
// same lines -> L1-served reuse, no LDS staging, no vmcnt(0) drains). h1 goes
// through a 24KB LDS tile (1 write barrier); GEMM2 = h1 LDS reads + inline he.
// R11 evidence: barrier-free g2 streamed at 2.4 TB/s vs 0.85 for phased g1.
__global__ __launch_bounds__(256, 3) void face_embed_kernel(
    const float* __restrict__ x1, const int* __restrict__ et1, const float* __restrict__ ar1,
    const float* __restrict__ x2, const int* __restrict__ et2, const float* __restrict__ ar2,
    const float* __restrict__ b1g, const char* __restrict__ ws,
    float* __restrict__ out) {
  const int g = blockIdx.y;
  const float* x = g ? x2 : x1;
  const int* et  = g ? et2 : et1;
  const float* ar = g ? ar2 : ar1;
  float* o = out + (size_t)g * NN * HD;
  const int* idx = (const int*)(ws + OFF_IDX) + g * NN;
  const int totF = ((const int*)(ws + OFF_TOT))[g];
  const int nFB = (totF + 31) >> 5;
  const int bx = blockIdx.x;
  const int tid = threadIdx.x;

  if (bx >= nFB) {                       // ---- zero path (32 non-face rows/block) ----
    int totN = NN - totF;
    int base = (bx - nFB) * 32;
    if (base >= totN) return;
    const int* idxN = idx + totF;
    f32x4 z = {0.f, 0.f, 0.f, 0.f};
#pragma unroll
    for (int it = 0; it < 12; ++it) {
      int c = tid + it * 256;            // 32 rows x 96 f32x4 chunks = 3072
      int r = c / 96, cc = c % 96;
      if (base + r < totN) {
        int node = idxN[base + r];
        *(f32x4*)(o + (size_t)node * HD + cc * 4) = z;
      }
    }
    return;
  }

  // ---- GEMM path ----
  __shared__ short h1s[32 * 384];        // 24576 B, XOR-swizzled bytes
  __shared__ int sN[32];

  const bf16x8* B1 = (const bf16x8*)(ws + OFF_B1);
  const bf16x8* B2 = (const bf16x8*)(ws + OFF_B2);
  const float* Tg  = (const float*)(ws + OFF_T);
  const float* Vg  = (const float*)(ws + OFF_V);
  const float* Big = (const float*)(ws + OFF_BI);

  const int row0 = bx * 32;
  if (tid < 32) sN[tid] = (row0 + tid < totF) ? idx[row0 + tid] : -1;
  __syncthreads();                       // barrier 1

  const int wid = tid >> 6, lane = tid & 63;
  const int lr = lane & 15, gq = lane >> 4;

  float b1c[6], b2c[6];
#pragma unroll
  for (int n = 0; n < 6; ++n) {
    int col = (wid * 6 + n) * 16 + lr;
    b1c[n] = b1g[col];
    b2c[n] = Big[col];
  }
  int nde[2]; float nda[2];
  const float* xp[2];
#pragma unroll
  for (int m = 0; m < 2; ++m) {
    int node = sN[m * 16 + lr];
    if (node >= 0) { nde[m] = et[node]; nda[m] = ar[node]; }
    else           { nde[m] = 0;        nda[m] = 0.f; node = sN[0]; }
    xp[m] = x + (size_t)node * 700;
  }

  f32x4 acc[2][6] = {};

  // ======== GEMM1: A-frags straight from global (L1-shared across waves) ========
  for (int kt = 0; kt < K1T; ++kt) {
    int k0 = kt * 32 + gq * 8;
    Frag a[2];
#pragma unroll
    for (int m = 0; m < 2; ++m) {
      const float* p = xp[m] + k0;
      f32x4 lo = *(const f32x4*)p;
      f32x4 hi;
      if (kt == 21 && gq == 3) hi = (f32x4){0.f, 0.f, 0.f, 0.f};  // k 700..703 pad
      else                     hi = *(const f32x4*)(p + 4);
#pragma unroll
      for (int i = 0; i < 4; ++i) { a[m].s[i] = f2bf(lo[i]); a[m].s[4 + i] = f2bf(hi[i]); }
    }
#pragma unroll
    for (int n = 0; n < 6; ++n) {
      bf16x8 b = B1[((wid * 6 + n) * K1T + kt) * 64 + lane];
#pragma unroll
      for (int m = 0; m < 2; ++m)
        acc[m][n] = __builtin_amdgcn_mfma_f32_16x16x32_bf16(a[m].v, b, acc[m][n], 0, 0, 0);
    }
  }

  // ======== h1 = elu(acc + b1) -> LDS swizzled; acc reset ========
#pragma unroll
  for (int m = 0; m < 2; ++m)
#pragma unroll
    for (int n = 0; n < 6; ++n) {
      int col = (wid * 6 + n) * 16 + lr;
#pragma unroll
      for (int r2 = 0; r2 < 4; ++r2) {
        int row = m * 16 + 4 * gq + r2;
        float hv = elu(acc[m][n][r2] + b1c[n]);
        int byte = (row * 768 + col * 2) ^ ((row & 15) << 4);
        *(short*)((char*)h1s + byte) = f2bf(hv);
      }
    }
  __syncthreads();                       // barrier 2

#pragma unroll
  for (int m = 0; m < 2; ++m)
#pragma unroll
    for (int n = 0; n < 6; ++n)
      acc[m][n] = (f32x4){0.f, 0.f, 0.f, 0.f};

  // ======== GEMM2: out = [h1|he] @ [W2g;W2e], single loop, he inline ========
  for (int kt = 0; kt < K2T; ++kt) {
    Frag a[2];
    if (kt < 12) {
#pragma unroll
      for (int m = 0; m < 2; ++m) {
        int row = m * 16 + lr;
        int byte = (row * 768 + (kt * 32 + gq * 8) * 2) ^ ((row & 15) << 4);
        a[m].v = *(const bf16x8*)((const char*)h1s + byte);
      }
    } else {
      int c0 = (kt - 12) * 32 + gq * 8;
#pragma unroll
      for (int m = 0; m < 2; ++m) {
        const float* Tp = Tg + nde[m] * 384 + c0;
        const float* Vp = Vg + c0;
#pragma unroll
        for (int i = 0; i < 8; ++i)
          a[m].s[i] = f2bf(elu(Tp[i] + nda[m] * Vp[i]));
      }
    }
#pragma unroll
    for (int n = 0; n < 6; ++n) {
      bf16x8 b = B2[((wid * 6 + n) * K2T + kt) * 64 + lane];
#pragma unroll
      for (int m = 0; m < 2; ++m)
        acc[m][n] = __builtin_amdgcn_mfma_f32_16x16x32_bf16(a[m].v, b, acc[m][n], 0, 0, 0);
    }
  }

  // ======== epilogue: +bias2, scatter store (384B line-aligned per wave) ========
#pragma unroll
  for (int m = 0; m < 2; ++m) {
#pragma unroll
    for (int r2 = 0; r2 < 4; ++r2) {
      int node = sN[m * 16 + 4 * gq + r2];
      if (node >= 0) {
#pragma unroll
        for (int n = 0; n < 6; ++n) {
          int col = (wid * 6 + n) * 16 + lr;
          o[(size_t)node * HD + col] = acc[m][n][r2] + b2c[n];
        }
      }
    }
  }
}

extern "C" void kernel_launch(void* const* d_in, const int* in_sizes, int n_in,
                              void* d_out, int out_size, void* d_ws, size_t ws_size,
                              hipStream_t stream) {
  (void)n_in; (void)out_size; (void)ws_size; (void)in_sizes;
  const float* x1  = (const float*)d_in[0];
  const float* is1 = (const float*)d_in[1];
  const int*   et1 = (const int*)d_in[2];
  const float* ar1 = (const float*)d_in[3];
  const float* x2  = (const float*)d_in[4];
  const float* is2 = (const float*)d_in[5];
  const int*   et2 = (const int*)d_in[6];
  const float* ar2 = (const float*)d_in[7];
  const float* W1g = (const float*)d_in[8];
  const float* b1g = (const float*)d_in[9];
  const float* W2g = (const float*)d_in[10];
  const float* b2g = (const float*)d_in[11];
  const float* W1e = (const float*)d_in[12];
  const float* b1e = (const float*)d_in[13];
  const float* W2e = (const float*)d_in[14];
  const float* b2e = (const float*)d_in[15];
  float* out = (float*)d_out;
  char* ws = (char*)d_ws;

  prep_kernel<<<dim3(288), dim3(256), 0, stream>>>(W1g, b1g, W2g, b2g, W1e, b1e, W2e, b2e, ws);
  count_kernel<<<dim3(NBLK, 2), dim3(1024), 0, stream>>>(is1, is2, ws);
  scan_kernel<<<dim3(1), dim3(64), 0, stream>>>(ws);
  compact_kernel<<<dim3(NBLK, 2), dim3(1024), 0, stream>>>(is1, is2, ws);

  dim3 grid(NN / 32 + 1, 2);
  face_embed_kernel<<<grid, dim3(256), 0, stream>>>(
      x1, et1, ar1, x2, et2, ar2, b1g, ws, out);
}

// Round 13
// 390.461 us; speedup vs baseline: 2.2869x; 1.0252x over previous
//
#include <hip/hip_runtime.h>
#include <hip/hip_bf16.h>

typedef __attribute__((ext_vector_type(8))) short short8;
typedef __attribute__((ext_vector_type(4))) short svec4;
typedef __attribute__((ext_vector_type(8))) __bf16 bf16x8;
typedef __attribute__((ext_vector_type(4))) float f32x4;

#define NN 100000
#define HD 384
#define K1T 22   // GEMM1 k-tiles (704/32; 700 padded)
#define K2T 24   // GEMM2 k-tiles ([h1 | he])
#define NBLK 98

// d_ws byte offsets
#define OFF_B1  0
#define OFF_B2  540672
#define OFF_T   1130496
#define OFF_V   1139712
#define OFF_BI  1141248
#define OFF_IDX 1142784
#define OFF_CNT 1942784
#define OFF_OFFS 1943568
#define OFF_TOT 1944352

union Frag { short s[8]; bf16x8 v; };

__device__ __forceinline__ short f2bf(float f) {
  union { __bf16 h; short s; } u;
  u.h = (__bf16)f;
  return u.s;
}

__device__ __forceinline__ float elu(float v) {
  return v > 0.f ? v : __expf(v) - 1.f;
}

__global__ void prep_kernel(const float* __restrict__ W1g, const float* __restrict__ b1g,
                            const float* __restrict__ W2g, const float* __restrict__ b2g,
                            const float* __restrict__ W1e, const float* __restrict__ b1e,
                            const float* __restrict__ W2e, const float* __restrict__ b2e,
                            char* __restrict__ ws) {
  int t = blockIdx.x * 256 + threadIdx.x;
  short* B1 = (short*)(ws + OFF_B1);
  short* B2 = (short*)(ws + OFF_B2);
  float* Tt = (float*)(ws + OFF_T);
  float* Vt = (float*)(ws + OFF_V);
  float* Bi = (float*)(ws + OFF_BI);
  if (t < 33792) {                       // B1: (nt,kt,lane) -> 8 shorts
    int lane = t & 63, rest = t >> 6;
    int kt = rest % K1T, nt = rest / K1T;
    int col = nt * 16 + (lane & 15);
    int kb = kt * 32 + (lane >> 4) * 8;
    short8 v;
#pragma unroll
    for (int i = 0; i < 8; ++i) {
      int k = kb + i;
      v[i] = (k < 700) ? f2bf(W1g[k * 384 + col]) : (short)0;
    }
    *(short8*)(B1 + (size_t)t * 8) = v;
  } else if (t < 70656) {                // B2
    int t2 = t - 33792;
    int lane = t2 & 63, rest = t2 >> 6;
    int kt = rest % K2T, nt = rest / K2T;
    int col = nt * 16 + (lane & 15);
    int kb = kt * 32 + (lane >> 4) * 8;
    short8 v;
#pragma unroll
    for (int i = 0; i < 8; ++i) {
      int k = kb + i;
      v[i] = (k < 384) ? f2bf(W2g[k * 384 + col]) : f2bf(W2e[(k - 384) * 384 + col]);
    }
    *(short8*)(B2 + (size_t)t2 * 8) = v;
  } else if (t < 73728) {                // tables
    int r = t - 70656;
    int which = r / 384, c = r % 384;
    if (which < 6)       Tt[r] = W1e[which * 384 + c] + b1e[c];
    else if (which == 6) Vt[c] = W1e[6 * 384 + c];
    else                 Bi[c] = b2g[c] + b2e[c];
  }
}

__global__ void count_kernel(const float* __restrict__ isf1, const float* __restrict__ isf2,
                             char* __restrict__ ws) {
  int g = blockIdx.y;
  const float* isf = g ? isf2 : isf1;
  int i = blockIdx.x * 1024 + threadIdx.x;
  bool face = (i < NN) && (isf[i] > 0.5f);
  unsigned long long b = __ballot(face);
  __shared__ int wc[16];
  int lane = threadIdx.x & 63, wid = threadIdx.x >> 6;
  if (lane == 0) wc[wid] = __popcll(b);
  __syncthreads();
  if (threadIdx.x == 0) {
    int s = 0;
#pragma unroll
    for (int w = 0; w < 16; ++w) s += wc[w];
    ((int*)(ws + OFF_CNT))[g * NBLK + blockIdx.x] = s;
  }
}

__global__ void scan_kernel(char* __restrict__ ws) {
  int t = threadIdx.x;
  if (t < 2) {
    const int* cnt = (const int*)(ws + OFF_CNT) + t * NBLK;
    int* offs = (int*)(ws + OFF_OFFS) + t * NBLK;
    int* tot = (int*)(ws + OFF_TOT);
    int run = 0;
    for (int b = 0; b < NBLK; ++b) { offs[b] = run; run += cnt[b]; }
    tot[t] = run;
  }
}

__global__ void compact_kernel(const float* __restrict__ isf1, const float* __restrict__ isf2,
                               char* __restrict__ ws) {
  int g = blockIdx.y;
  const float* isf = g ? isf2 : isf1;
  const int* offs = (const int*)(ws + OFF_OFFS) + g * NBLK;
  int totF = ((const int*)(ws + OFF_TOT))[g];
  int* idx = (int*)(ws + OFF_IDX) + g * NN;
  int bx = blockIdx.x;
  int i = bx * 1024 + threadIdx.x;
  bool valid = i < NN;
  bool face = valid && (isf[i] > 0.5f);
  unsigned long long bf = __ballot(face);
  unsigned long long bv = __ballot(valid);
  int lane = threadIdx.x & 63, wid = threadIdx.x >> 6;
  __shared__ int wF[16], wV[16];
  if (lane == 0) { wF[wid] = __popcll(bf); wV[wid] = __popcll(bv); }
  __syncthreads();
  int baseF = 0, baseV = 0;
  for (int w = 0; w < wid; ++w) { baseF += wF[w]; baseV += wV[w]; }
  unsigned long long lmask = (1ull << lane) - 1ull;
  int pF = __popcll(bf & lmask);
  int pV = __popcll(bv & lmask);
  if (face) {
    idx[offs[bx] + baseF + pF] = i;
  } else if (valid) {
    int nfBefore = bx * 1024 - offs[bx];
    int nfIn = (baseV + pV) - (baseF + pF);
    idx[totF + nfBefore + nfIn] = i;
  }
}

// 32 gathered face rows/block, 4 waves N-split (wave = 32r x 96c), acc[2][6]
// reused for both GEMMs. Barrier-light (2 barriers): GEMM1 A-frags direct from
// global (L1-shared across waves); h1 via 24KB LDS tile; GEMM2 h1 + inline he.
// launch_bounds(256,4): unified budget 512/4=128 >= 68 arch + 48 acc = 116.
// (R10's spill at this bound was its extra st[6] staging regs -> 140 > 128.)
// LDS 24.6KB permits 6 blocks/CU; VGPR caps at 4 blocks/CU = 16 waves/CU.
__global__ __launch_bounds__(256, 4) void face_embed_kernel(
    const float* __restrict__ x1, const int* __restrict__ et1, const float* __restrict__ ar1,
    const float* __restrict__ x2, const int* __restrict__ et2, const float* __restrict__ ar2,
    const float* __restrict__ b1g, const char* __restrict__ ws,
    float* __restrict__ out) {
  const int g = blockIdx.y;
  const float* x = g ? x2 : x1;
  const int* et  = g ? et2 : et1;
  const float* ar = g ? ar2 : ar1;
  float* o = out + (size_t)g * NN * HD;
  const int* idx = (const int*)(ws + OFF_IDX) + g * NN;
  const int totF = ((const int*)(ws + OFF_TOT))[g];
  const int nFB = (totF + 31) >> 5;
  const int bx = blockIdx.x;
  const int tid = threadIdx.x;

  if (bx >= nFB) {                       // ---- zero path (32 non-face rows/block) ----
    int totN = NN - totF;
    int base = (bx - nFB) * 32;
    if (base >= totN) return;
    const int* idxN = idx + totF;
    f32x4 z = {0.f, 0.f, 0.f, 0.f};
#pragma unroll
    for (int it = 0; it < 12; ++it) {
      int c = tid + it * 256;            // 32 rows x 96 f32x4 chunks = 3072
      int r = c / 96, cc = c % 96;
      if (base + r < totN) {
        int node = idxN[base + r];
        *(f32x4*)(o + (size_t)node * HD + cc * 4) = z;
      }
    }
    return;
  }

  // ---- GEMM path ----
  __shared__ short h1s[32 * 384];        // 24576 B, XOR-swizzled bytes
  __shared__ int sN[32];

  const bf16x8* B1 = (const bf16x8*)(ws + OFF_B1);
  const bf16x8* B2 = (const bf16x8*)(ws + OFF_B2);
  const float* Tg  = (const float*)(ws + OFF_T);
  const float* Vg  = (const float*)(ws + OFF_V);
  const float* Big = (const float*)(ws + OFF_BI);

  const int row0 = bx * 32;
  if (tid < 32) sN[tid] = (row0 + tid < totF) ? idx[row0 + tid] : -1;
  __syncthreads();                       // barrier 1

  const int wid = tid >> 6, lane = tid & 63;
  const int lr = lane & 15, gq = lane >> 4;

  float b1c[6], b2c[6];
#pragma unroll
  for (int n = 0; n < 6; ++n) {
    int col = (wid * 6 + n) * 16 + lr;
    b1c[n] = b1g[col];
    b2c[n] = Big[col];
  }
  int nde[2]; float nda[2];
  const float* xp[2];
#pragma unroll
  for (int m = 0; m < 2; ++m) {
    int node = sN[m * 16 + lr];
    if (node >= 0) { nde[m] = et[node]; nda[m] = ar[node]; }
    else           { nde[m] = 0;        nda[m] = 0.f; node = sN[0]; }
    xp[m] = x + (size_t)node * 700;
  }

  f32x4 acc[2][6] = {};

  // ======== GEMM1: A-frags straight from global (L1-shared across waves) ========
  for (int kt = 0; kt < K1T; ++kt) {
    int k0 = kt * 32 + gq * 8;
    Frag a[2];
#pragma unroll
    for (int m = 0; m < 2; ++m) {
      const float* p = xp[m] + k0;
      f32x4 lo = *(const f32x4*)p;
      f32x4 hi;
      if (kt == 21 && gq == 3) hi = (f32x4){0.f, 0.f, 0.f, 0.f};  // k 700..703 pad
      else                     hi = *(const f32x4*)(p + 4);
#pragma unroll
      for (int i = 0; i < 4; ++i) { a[m].s[i] = f2bf(lo[i]); a[m].s[4 + i] = f2bf(hi[i]); }
    }
#pragma unroll
    for (int n = 0; n < 6; ++n) {
      bf16x8 b = B1[((wid * 6 + n) * K1T + kt) * 64 + lane];
#pragma unroll
      for (int m = 0; m < 2; ++m)
        acc[m][n] = __builtin_amdgcn_mfma_f32_16x16x32_bf16(a[m].v, b, acc[m][n], 0, 0, 0);
    }
  }

  // ======== h1 = elu(acc + b1) -> LDS swizzled; acc reset ========
#pragma unroll
  for (int m = 0; m < 2; ++m)
#pragma unroll
    for (int n = 0; n < 6; ++n) {
      int col = (wid * 6 + n) * 16 + lr;
#pragma unroll
      for (int r2 = 0; r2 < 4; ++r2) {
        int row = m * 16 + 4 * gq + r2;
        float hv = elu(acc[m][n][r2] + b1c[n]);
        int byte = (row * 768 + col * 2) ^ ((row & 15) << 4);
        *(short*)((char*)h1s + byte) = f2bf(hv);
      }
    }
  __syncthreads();                       // barrier 2

#pragma unroll
  for (int m = 0; m < 2; ++m)
#pragma unroll
    for (int n = 0; n < 6; ++n)
      acc[m][n] = (f32x4){0.f, 0.f, 0.f, 0.f};

  // ======== GEMM2: out = [h1|he] @ [W2g;W2e], single loop, he inline ========
  for (int kt = 0; kt < K2T; ++kt) {
    Frag a[2];
    if (kt < 12) {
#pragma unroll
      for (int m = 0; m < 2; ++m) {
        int row = m * 16 + lr;
        int byte = (row * 768 + (kt * 32 + gq * 8) * 2) ^ ((row & 15) << 4);
        a[m].v = *(const bf16x8*)((const char*)h1s + byte);
      }
    } else {
      int c0 = (kt - 12) * 32 + gq * 8;
#pragma unroll
      for (int m = 0; m < 2; ++m) {
        const float* Tp = Tg + nde[m] * 384 + c0;
        const float* Vp = Vg + c0;
#pragma unroll
        for (int i = 0; i < 8; ++i)
          a[m].s[i] = f2bf(elu(Tp[i] + nda[m] * Vp[i]));
      }
    }
#pragma unroll
    for (int n = 0; n < 6; ++n) {
      bf16x8 b = B2[((wid * 6 + n) * K2T + kt) * 64 + lane];
#pragma unroll
      for (int m = 0; m < 2; ++m)
        acc[m][n] = __builtin_amdgcn_mfma_f32_16x16x32_bf16(a[m].v, b, acc[m][n], 0, 0, 0);
    }
  }

  // ======== epilogue: +bias2, scatter store (384B line-aligned per wave) ========
#pragma unroll
  for (int m = 0; m < 2; ++m) {
#pragma unroll
    for (int r2 = 0; r2 < 4; ++r2) {
      int node = sN[m * 16 + 4 * gq + r2];
      if (node >= 0) {
#pragma unroll
        for (int n = 0; n < 6; ++n) {
          int col = (wid * 6 + n) * 16 + lr;
          o[(size_t)node * HD + col] = acc[m][n][r2] + b2c[n];
        }
      }
    }
  }
}

extern "C" void kernel_launch(void* const* d_in, const int* in_sizes, int n_in,
                              void* d_out, int out_size, void* d_ws, size_t ws_size,
                              hipStream_t stream) {
  (void)n_in; (void)out_size; (void)ws_size; (void)in_sizes;
  const float* x1  = (const float*)d_in[0];
  const float* is1 = (const float*)d_in[1];
  const int*   et1 = (const int*)d_in[2];
  const float* ar1 = (const float*)d_in[3];
  const float* x2  = (const float*)d_in[4];
  const float* is2 = (const float*)d_in[5];
  const int*   et2 = (const int*)d_in[6];
  const float* ar2 = (const float*)d_in[7];
  const float* W1g = (const float*)d_in[8];
  const float* b1g = (const float*)d_in[9];
  const float* W2g = (const float*)d_in[10];
  const float* b2g = (const float*)d_in[11];
  const float* W1e = (const float*)d_in[12];
  const float* b1e = (const float*)d_in[13];
  const float* W2e = (const float*)d_in[14];
  const float* b2e = (const float*)d_in[15];
  float* out = (float*)d_out;
  char* ws = (char*)d_ws;

  prep_kernel<<<dim3(288), dim3(256), 0, stream>>>(W1g, b1g, W2g, b2g, W1e, b1e, W2e, b2e, ws);
  count_kernel<<<dim3(NBLK, 2), dim3(1024), 0, stream>>>(is1, is2, ws);
  scan_kernel<<<dim3(1), dim3(64), 0, stream>>>(ws);
  compact_kernel<<<dim3(NBLK, 2), dim3(1024), 0, stream>>>(is1, is2, ws);

  dim3 grid(NN / 32 + 1, 2);
  face_embed_kernel<<<grid, dim3(256), 0, stream>>>(
      x1, et1, ar1, x2, et2, ar2, b1g, ws, out);
}